// Round 16
// baseline (210.488 us; speedup 1.0000x reference)
//
#include <hip/hip_runtime.h>
#include <hip/hip_bf16.h>
#include <stdint.h>

#define NT 20000
#define DIM 1024
#define HID 512
#define DATT_N 256
#define NCLUS 10
#define NCLS_N 4
#define NBS 79        // ceil(NT/256) scatter blocks
#define NRTX 40       // max 128-row tiles per cluster (cnt_c ~2000 +/- 42)

typedef __bf16 bf16;
typedef __attribute__((ext_vector_type(8))) __bf16 bf16x8;
typedef __attribute__((ext_vector_type(4))) float f32x4;

__device__ __forceinline__ void gload_lds16(const void* g, void* l) {
  __builtin_amdgcn_global_load_lds(
      (const __attribute__((address_space(1))) unsigned int*)g,
      (__attribute__((address_space(3))) unsigned int*)l, 16, 0, 0);
}

// ---------------- K1: setup = scatter(self-sufficient) + zero + x-cast + W transposes ----------------

#define ZPB 20                       // zero blocks (NCLUS*HID/256)
#define CASTB (NT * 64 / 256)        // 5000 cast blocks (16 elems/thread)
#define TW1B (32 * 4 * NCLUS)        // 1280 W1-transpose blocks (32x128 tiles)
#define TW2B (16 * 4 * NCLUS)        // 640  W2-transpose blocks

// 32x128 tile transpose-cast: dst[b][j][i] = bf16(src[b][i][j])
__device__ __forceinline__ void tr_body(const float* __restrict__ s, bf16* __restrict__ d,
                                        int R, int Cc, int i0, int j0, float (*t)[128]) {
  int tid = threadIdx.x;
  int cr = tid >> 5;                 // 0..7
  int cc4 = (tid & 31) << 2;         // 0..124 step 4
#pragma unroll
  for (int yy = 0; yy < 32; yy += 8)
    *(f32x4*)&t[yy + cr][cc4] = *(const f32x4*)&s[(size_t)(i0 + yy + cr) * Cc + j0 + cc4];
  __syncthreads();
  int col = tid >> 1, h = (tid & 1) << 4;
  bf16 tmp[16];
#pragma unroll
  for (int k = 0; k < 16; ++k) tmp[k] = (bf16)t[h + k][col];
  *(bf16x8*)&d[(size_t)(j0 + col) * R + i0 + h] = *(bf16x8*)&tmp[0];
  *(bf16x8*)&d[(size_t)(j0 + col) * R + i0 + h + 8] = *(bf16x8*)&tmp[8];
}

__global__ __launch_bounds__(256) void setup_kernel(
    const int* __restrict__ cid,
    int* __restrict__ cnt, int* __restrict__ offs, int* __restrict__ order,
    float* __restrict__ pool, float* __restrict__ score,
    const float* __restrict__ x, bf16* __restrict__ xs,
    const float* __restrict__ W1, bf16* __restrict__ w1t,
    const float* __restrict__ W2, bf16* __restrict__ w2t) {
  __shared__ float t[32][128];
  int b = blockIdx.x;
  int tid = threadIdx.x;
  if (b < NBS) {
    // self-sufficient scatter: re-derive global histogram by scanning all chunks
    __shared__ int sbase[16];   // tokens of cluster c in chunks < b
    __shared__ int scnt[16];    // total tokens of cluster c
    __shared__ int soffs[17];
    __shared__ int wcnt[4][16];
    __shared__ int wbase[4][16];
    if (tid < 16) { sbase[tid] = 0; scnt[tid] = 0; }
    __syncthreads();
    int lane = tid & 63, w = tid >> 6;
    int n = b * 256 + tid;
    int mycid = (n < NT) ? cid[n] : -1;
    unsigned long long lmask = (lane == 63) ? ~0ull >> 1 : (1ull << lane) - 1;
    int myrank = 0;
    for (int bb = 0; bb < NBS; ++bb) {
      int nn = bb * 256 + tid;
      int cc = (nn < NT) ? cid[nn] : -1;
#pragma unroll
      for (int c = 0; c < NCLUS; ++c) {
        unsigned long long m = __ballot(cc == c);
        if (bb == b && mycid == c && cc == c) myrank = __popcll(m & lmask);
        if (lane == c) {
          int cw = __popcll(m);
          if (cw) {
            if (bb < b) atomicAdd(&sbase[c], cw);
            atomicAdd(&scnt[c], cw);
          }
          if (bb == b) wcnt[w][c] = cw;
        }
      }
    }
    __syncthreads();
    if (tid == 0) {
      int a = 0;
      for (int i = 0; i < NCLUS; ++i) { soffs[i] = a; a += scnt[i]; }
      soffs[NCLUS] = a;
    }
    __syncthreads();
    if (b == 0 && tid <= NCLUS) {
      if (tid < NCLUS) cnt[tid] = scnt[tid];
      offs[tid] = soffs[tid];
    }
    if (tid < NCLUS) {
      int pre = sbase[tid];
#pragma unroll
      for (int ww = 0; ww < 4; ++ww) { wbase[ww][tid] = pre; pre += wcnt[ww][tid]; }
    }
    __syncthreads();
    if (n < NT) order[soffs[mycid] + wbase[w][mycid] + myrank] = n;
  } else if (b < NBS + ZPB) {
    int i = (b - NBS) * 256 + tid;
    if (i < NCLUS * HID) pool[i] = 0.f;
    if (b == NBS && tid < 16) score[tid] = 0.f;
  } else if (b < NBS + ZPB + CASTB) {
    int tt = (b - NBS - ZPB) * 256 + tid;  // one thread per 16 elements
    size_t base = (size_t)tt << 4;
    if (base < (size_t)NT * DIM) {
      const f32x4* p = (const f32x4*)(x + base);
      f32x4 u0 = p[0], v0 = p[1], u1 = p[2], v1 = p[3];
      bf16x8 w0, w1;
      w0[0] = (bf16)u0[0]; w0[1] = (bf16)u0[1]; w0[2] = (bf16)u0[2]; w0[3] = (bf16)u0[3];
      w0[4] = (bf16)v0[0]; w0[5] = (bf16)v0[1]; w0[6] = (bf16)v0[2]; w0[7] = (bf16)v0[3];
      w1[0] = (bf16)u1[0]; w1[1] = (bf16)u1[1]; w1[2] = (bf16)u1[2]; w1[3] = (bf16)u1[3];
      w1[4] = (bf16)v1[0]; w1[5] = (bf16)v1[1]; w1[6] = (bf16)v1[2]; w1[7] = (bf16)v1[3];
      bf16* q = xs + base;
      *(bf16x8*)q = w0;
      *(bf16x8*)(q + 8) = w1;
    }
  } else if (b < NBS + ZPB + CASTB + TW1B) {
    int bb = b - NBS - ZPB - CASTB;  // z*128 + rt*4 + ct ; R=DIM rows, Cc=HID cols
    int z = bb >> 7, r = bb & 127, rt = r >> 2, ct = r & 3;
    tr_body(W1 + (size_t)z * DIM * HID, w1t + (size_t)z * DIM * HID,
            DIM, HID, rt * 32, ct * 128, t);
  } else {
    int bb = b - NBS - ZPB - CASTB - TW1B; // z*64 + rt*4 + ct ; R=HID, Cc=HID
    int z = bb >> 6, r = bb & 63, rt = r >> 2, ct = r & 3;
    tr_body(W2 + (size_t)z * HID * HID, w2t + (size_t)z * HID * HID,
            HID, HID, rt * 32, ct * 128, t);
  }
}

// XCD-grouping decode over NRTX tiles/cluster
__device__ __forceinline__ bool decode_grp(int d, int& c, int& rt, int& j) {
  int x8 = d & 7, s = d >> 3;
  int g = (s >> 2) * 8 + x8;
  if (g >= NRTX * NCLUS) return false;
  j = s & 3;
  c = g / NRTX;
  rt = g - c * NRTX;
  return true;
}

// ---------------- GEMM1: h1 = relu(x[order] @ W1[c]^T + b1[c]) ----------------
// 128x128 tile, BK=64, 4 waves, T2 both-sides XOR swizzle (rule 21).
// launch_bounds (256,2): VGPR 84, no spill (R15 lesson: min-waves 4 forced
// VGPR<=64 -> spills, +44 MB scratch writes).

__global__ __launch_bounds__(256, 2) void gemm1_kernel(
    const bf16* __restrict__ xs, const int* __restrict__ order,
    const bf16* __restrict__ w1t, const float* __restrict__ b1,
    const int* __restrict__ offs, const int* __restrict__ cnt, bf16* __restrict__ h1) {
  int c, rt, j;
  if (!decode_grp(blockIdx.x, c, rt, j)) return;
  int cntc = cnt[c];
  int row0 = rt * 128;
  if (row0 >= cntc) return;
  int seg = offs[c];
  int n0 = j * 128;

  __shared__ bf16 Als[128 * 64];  // [row][slot-swizzled k]
  __shared__ bf16 Bls[128 * 64];
  __shared__ int s_ord[128];

  int tid = threadIdx.x;
  int lane = tid & 63, wid = tid >> 6;
  if (tid < 128) {
    int ar = seg + row0 + tid; if (ar > NT - 1) ar = NT - 1;
    s_ord[tid] = order[ar];
  }
  __syncthreads();

  int wr = wid >> 1, wc = wid & 1;
  int rx = lane & 7, hi = lane >> 4;
  int kswz = ((lane & 7) ^ (lane >> 3)) << 3;   // source-swizzled 16B slot

  const bf16* aptr[4]; int aoff[4];
  const bf16* bptr[4]; int boff[4];
#pragma unroll
  for (int i = 0; i < 4; ++i) {
    int chunk = i * 4 + wid;              // 0..15, 8 rows x 64 k each
    int r = chunk * 8 + (lane >> 3);      // tile row 0..127
    aptr[i] = xs + (size_t)s_ord[r] * DIM + kswz;
    aoff[i] = chunk * 512;
    bptr[i] = w1t + (size_t)(c * HID + n0 + r) * DIM + kswz;
    boff[i] = chunk * 512;
  }

  f32x4 acc[4][4];
#pragma unroll
  for (int m = 0; m < 4; m++)
#pragma unroll
    for (int n = 0; n < 4; n++) acc[m][n] = {0.f, 0.f, 0.f, 0.f};

  for (int k0 = 0; k0 < DIM; k0 += 64) {
#pragma unroll
    for (int i = 0; i < 4; ++i) gload_lds16(aptr[i] + k0, &Als[aoff[i]]);
#pragma unroll
    for (int i = 0; i < 4; ++i) gload_lds16(bptr[i] + k0, &Bls[boff[i]]);
    __syncthreads();
#pragma unroll
    for (int ks = 0; ks < 2; ++ks) {
      int t16 = ks * 4 + hi;              // true 16B-slot index
      int ko = ((t16 ^ rx) << 3);         // swizzled read slot
      bf16x8 a[4], b[4];
#pragma unroll
      for (int m = 0; m < 4; m++)
        a[m] = *(const bf16x8*)(&Als[(wr * 64 + m * 16 + (lane & 15)) * 64 + ko]);
#pragma unroll
      for (int n = 0; n < 4; n++)
        b[n] = *(const bf16x8*)(&Bls[(wc * 64 + n * 16 + (lane & 15)) * 64 + ko]);
#pragma unroll
      for (int m = 0; m < 4; m++)
#pragma unroll
        for (int n = 0; n < 4; n++)
          acc[m][n] = __builtin_amdgcn_mfma_f32_16x16x32_bf16(a[m], b[n], acc[m][n], 0, 0, 0);
    }
    __syncthreads();
  }

  int valid = cntc - row0; if (valid > 128) valid = 128;
#pragma unroll
  for (int n = 0; n < 4; n++) {
    int col = n0 + wc * 64 + n * 16 + (lane & 15);
    float bias = b1[c * HID + col];
#pragma unroll
    for (int m = 0; m < 4; m++) {
      int rbase = wr * 64 + m * 16 + ((lane >> 4) << 2);
#pragma unroll
      for (int e = 0; e < 4; e++) {
        int r = rbase + e;
        if (r < valid) {
          float v = acc[m][n][e] + bias;
          h1[(size_t)(seg + row0 + r) * HID + col] = (bf16)(v > 0.f ? v : 0.f);
        }
      }
    }
  }
}

// ---------------- GEMM2: pool[c] += colsum(relu(h1 @ W2[c]^T + b2[c])) ----------------

__global__ __launch_bounds__(256, 2) void gemm2_kernel(
    const bf16* __restrict__ h1, const bf16* __restrict__ w2t, const float* __restrict__ b2,
    const int* __restrict__ offs, const int* __restrict__ cnt, float* __restrict__ pool) {
  int c, rt, j;
  if (!decode_grp(blockIdx.x, c, rt, j)) return;
  int cntc = cnt[c];
  int row0 = rt * 128;
  if (row0 >= cntc) return;
  int seg = offs[c];
  int n0 = j * 128;
  int valid = cntc - row0; if (valid > 128) valid = 128;

  __shared__ bf16 Als[128 * 64];
  __shared__ bf16 Bls[128 * 64];

  int tid = threadIdx.x;
  int lane = tid & 63, wid = tid >> 6;
  int wr = wid >> 1, wc = wid & 1;
  int rx = lane & 7, hi = lane >> 4;
  int kswz = ((lane & 7) ^ (lane >> 3)) << 3;

  const bf16* aptr[4]; int aoff[4];
  const bf16* bptr[4]; int boff[4];
#pragma unroll
  for (int i = 0; i < 4; ++i) {
    int chunk = i * 4 + wid;
    int r = chunk * 8 + (lane >> 3);
    int ar = seg + row0 + r; if (ar > NT - 1) ar = NT - 1;
    aptr[i] = h1 + (size_t)ar * HID + kswz;
    aoff[i] = chunk * 512;
    bptr[i] = w2t + (size_t)(c * HID + n0 + r) * HID + kswz;
    boff[i] = chunk * 512;
  }

  f32x4 acc[4][4];
#pragma unroll
  for (int m = 0; m < 4; m++)
#pragma unroll
    for (int n = 0; n < 4; n++) acc[m][n] = {0.f, 0.f, 0.f, 0.f};

  for (int k0 = 0; k0 < HID; k0 += 64) {
#pragma unroll
    for (int i = 0; i < 4; ++i) gload_lds16(aptr[i] + k0, &Als[aoff[i]]);
#pragma unroll
    for (int i = 0; i < 4; ++i) gload_lds16(bptr[i] + k0, &Bls[boff[i]]);
    __syncthreads();
#pragma unroll
    for (int ks = 0; ks < 2; ++ks) {
      int t16 = ks * 4 + hi;
      int ko = ((t16 ^ rx) << 3);
      bf16x8 a[4], b[4];
#pragma unroll
      for (int m = 0; m < 4; m++)
        a[m] = *(const bf16x8*)(&Als[(wr * 64 + m * 16 + (lane & 15)) * 64 + ko]);
#pragma unroll
      for (int n = 0; n < 4; n++)
        b[n] = *(const bf16x8*)(&Bls[(wc * 64 + n * 16 + (lane & 15)) * 64 + ko]);
#pragma unroll
      for (int m = 0; m < 4; m++)
#pragma unroll
        for (int n = 0; n < 4; n++)
          acc[m][n] = __builtin_amdgcn_mfma_f32_16x16x32_bf16(a[m], b[n], acc[m][n], 0, 0, 0);
    }
    __syncthreads();
  }

#pragma unroll
  for (int n = 0; n < 4; n++) {
    int col = n0 + wc * 64 + n * 16 + (lane & 15);
    float bias = b2[c * HID + col];
    float s = 0.f;
#pragma unroll
    for (int m = 0; m < 4; m++) {
      int rbase = wr * 64 + m * 16 + ((lane >> 4) << 2);
#pragma unroll
      for (int e = 0; e < 4; e++) {
        if (rbase + e < valid) {
          float v = acc[m][n][e] + bias;
          s += (v > 0.f ? v : 0.f);
        }
      }
    }
    s += __shfl_xor(s, 16);
    s += __shfl_xor(s, 32);
    if (lane < 16) atomicAdd(&pool[c * HID + n0 + wc * 64 + n * 16 + lane], s);
  }
}

// ---------------- tails (fp32, parallelized) ----------------

__global__ __launch_bounds__(256) void tail_fc(
    const float* __restrict__ pool, const int* __restrict__ cnt,
    const float* __restrict__ fcW, const float* __restrict__ fcb,
    float* __restrict__ hbuf) {
  int c = blockIdx.x >> 3;
  int jt = blockIdx.x & 7;
  __shared__ float hc[HID];
  __shared__ float red[4][64];
  int tid = threadIdx.x;
  float inv = 1.f / fmaxf((float)cnt[c], 1.f);
  for (int k = tid; k < HID; k += 256) hc[k] = pool[c * HID + k] * inv;
  __syncthreads();
  int jl = tid & 63, kg = tid >> 6;
  int j = jt * 64 + jl;
  float s = 0.f;
#pragma unroll 4
  for (int k = kg * 128; k < kg * 128 + 128; ++k) s += hc[k] * fcW[(size_t)k * HID + j];
  red[kg][jl] = s;
  __syncthreads();
  if (kg == 0) {
    float v = red[0][jl] + red[1][jl] + red[2][jl] + red[3][jl] + fcb[j];
    hbuf[c * HID + j] = fmaxf(v, 0.f);
  }
}

// 40 blocks: (cluster, 64-wide j slice); partial gated sums atomicAdd into score
__global__ __launch_bounds__(256) void tail_att(
    const float* __restrict__ hbuf,
    const float* __restrict__ Wa, const float* __restrict__ ba,
    const float* __restrict__ Wb, const float* __restrict__ bb,
    const float* __restrict__ Wc, const float* __restrict__ bc,
    float* __restrict__ score) {
  int c = blockIdx.x >> 2, js = blockIdx.x & 3;
  __shared__ float h[HID];
  __shared__ float ra[4][64];
  __shared__ float rb[4][64];
  __shared__ float sc[64];
  int tid = threadIdx.x;
  for (int k = tid; k < HID; k += 256) h[k] = hbuf[c * HID + k];
  __syncthreads();
  int jl = tid & 63, kg = tid >> 6;
  int j = js * 64 + jl;
  float sa = 0.f, sb = 0.f;
#pragma unroll 4
  for (int k = kg * 128; k < kg * 128 + 128; ++k) {
    float hv = h[k];
    sa += hv * Wa[(size_t)k * DATT_N + j];
    sb += hv * Wb[(size_t)k * DATT_N + j];
  }
  ra[kg][jl] = sa;
  rb[kg][jl] = sb;
  __syncthreads();
  if (kg == 0) {
    float va = ra[0][jl] + ra[1][jl] + ra[2][jl] + ra[3][jl] + ba[j];
    float vb = rb[0][jl] + rb[1][jl] + rb[2][jl] + rb[3][jl] + bb[j];
    float av = tanhf(va);
    float bv = 1.f / (1.f + expf(-vb));
    sc[jl] = av * bv * Wc[j];
  }
  __syncthreads();
  if (tid < 64) {
    float v = sc[tid];
#pragma unroll
    for (int w = 32; w > 0; w >>= 1) v += __shfl_xor(v, w);
    if (tid == 0) atomicAdd(&score[c], v + (js == 0 ? bc[0] : 0.f));
  }
}

// 1 block, 1024 thr: softmax(score) -> hp -> rho -> classifier -> out
__global__ __launch_bounds__(1024) void tail_fin(
    const float* __restrict__ score, const float* __restrict__ hbuf,
    const float* __restrict__ rhoW, const float* __restrict__ rhob,
    const float* __restrict__ clsW, const float* __restrict__ clsb,
    float* __restrict__ out) {
  __shared__ float Asm[NCLUS];
  __shared__ float hp[HID];
  __shared__ float rr[4][DATT_N];
  __shared__ float hr[DATT_N];
  __shared__ float lg[NCLS_N];
  int tid = threadIdx.x;
  if (tid == 0) {
    float mx = -1e30f;
    for (int c = 0; c < NCLUS; c++) mx = fmaxf(mx, score[c]);
    float sum = 0.f, e[NCLUS];
    for (int c = 0; c < NCLUS; c++) { e[c] = expf(score[c] - mx); sum += e[c]; }
    for (int c = 0; c < NCLUS; c++) Asm[c] = e[c] / sum;
  }
  __syncthreads();
  if (tid < HID) {
    float s = 0.f;
#pragma unroll
    for (int c = 0; c < NCLUS; c++) s += Asm[c] * hbuf[c * HID + tid];
    hp[tid] = s;
  }
  __syncthreads();
  int jl = tid & 255, kg = tid >> 8;
  float s = 0.f;
#pragma unroll 4
  for (int k = kg * 128; k < kg * 128 + 128; ++k) s += hp[k] * rhoW[(size_t)k * DATT_N + jl];
  rr[kg][jl] = s;
  __syncthreads();
  if (kg == 0) hr[jl] = fmaxf(rr[0][jl] + rr[1][jl] + rr[2][jl] + rr[3][jl] + rhob[jl], 0.f);
  __syncthreads();
  if (tid < NCLS_N * 64) {
    int t = tid >> 6, l = tid & 63;
    float cs = 0.f;
    for (int j = l; j < DATT_N; j += 64) cs += hr[j] * clsW[j * NCLS_N + t];
#pragma unroll
    for (int w = 32; w > 0; w >>= 1) cs += __shfl_xor(cs, w);
    if (l == 0) lg[t] = cs + clsb[t];
  }
  __syncthreads();
  if (tid == 0) {
    float mx = lg[0];
    int am = 0;
    for (int t = 1; t < NCLS_N; t++) if (lg[t] > mx) { mx = lg[t]; am = t; }
    float sum = 0.f, e[NCLS_N];
    for (int t = 0; t < NCLS_N; t++) { e[t] = expf(lg[t] - mx); sum += e[t]; }
    for (int t = 0; t < NCLS_N; t++) {
      out[t] = lg[t];
      out[NCLS_N + t] = e[t] / sum;
    }
    out[2 * NCLS_N] = (float)am;
  }
}

// ---------------- launch ----------------

extern "C" void kernel_launch(void* const* d_in, const int* in_sizes, int n_in,
                              void* d_out, int out_size, void* d_ws, size_t ws_size,
                              hipStream_t stream) {
  const float* x    = (const float*)d_in[0];
  const int*   cid  = (const int*)d_in[1];
  const float* W1   = (const float*)d_in[2];
  const float* b1   = (const float*)d_in[3];
  const float* W2   = (const float*)d_in[4];
  const float* b2   = (const float*)d_in[5];
  const float* fcW  = (const float*)d_in[6];
  const float* fcb  = (const float*)d_in[7];
  const float* Wa   = (const float*)d_in[8];
  const float* ba   = (const float*)d_in[9];
  const float* Wb   = (const float*)d_in[10];
  const float* bb   = (const float*)d_in[11];
  const float* Wc   = (const float*)d_in[12];
  const float* bc   = (const float*)d_in[13];
  const float* rhoW = (const float*)d_in[14];
  const float* rhob = (const float*)d_in[15];
  const float* clsW = (const float*)d_in[16];
  const float* clsb = (const float*)d_in[17];
  float* out = (float*)d_out;

  char* ws = (char*)d_ws;
  int*   cnt     = (int*)(ws + 0);
  int*   offs    = (int*)(ws + 64);
  float* score   = (float*)(ws + 128);                  // 16 floats
  int*   order   = (int*)(ws + 8192);                   // NT ints
  float* pool    = (float*)(ws + 8192 + 80000);
  float* hbuf    = (float*)(ws + 8192 + 80000 + NCLUS * HID * 4);
  size_t o = 8192 + 80000 + 2ull * NCLUS * HID * 4;
  o = (o + 255) & ~(size_t)255;
  bf16* w1t = (bf16*)(ws + o); o += (size_t)NCLUS * HID * DIM * 2;
  bf16* w2t = (bf16*)(ws + o); o += (size_t)NCLUS * HID * HID * 2;
  bf16* h1  = (bf16*)(ws + o); o += (size_t)NT * HID * 2;
  bf16* xs  = (bf16*)(ws + o); o += (size_t)NT * DIM * 2;

  setup_kernel<<<dim3(NBS + ZPB + CASTB + TW1B + TW2B), dim3(256), 0, stream>>>(
      cid, cnt, offs, order, pool, score, x, xs, W1, w1t, W2, w2t);

  int nblk = 8 * ((NRTX * NCLUS + 7) / 8) * 4;   // 1600
  gemm1_kernel<<<dim3(nblk), dim3(256), 0, stream>>>(xs, order, w1t, b1, offs, cnt, h1);
  gemm2_kernel<<<dim3(nblk), dim3(256), 0, stream>>>(h1, w2t, b2, offs, cnt, pool);

  tail_fc<<<dim3(NCLUS * 8), dim3(256), 0, stream>>>(pool, cnt, fcW, fcb, hbuf);
  tail_att<<<dim3(NCLUS * 4), dim3(256), 0, stream>>>(hbuf, Wa, ba, Wb, bb, Wc, bc, score);
  tail_fin<<<dim3(1), dim3(1024), 0, stream>>>(score, hbuf, rhoW, rhob, clsW, clsb, out);
}

// Round 17
// 123.206 us; speedup vs baseline: 1.7084x; 1.7084x over previous
//
#include <hip/hip_runtime.h>
#include <hip/hip_bf16.h>
#include <stdint.h>

#define NT 20000
#define DIM 1024
#define HID 512
#define DATT_N 256
#define NCLUS 10
#define NCLS_N 4
#define NBS 79        // ceil(NT/256) sort blocks
#define NRTX 40       // max 128-row tiles per cluster (cnt_c ~2000 +/- 42)

typedef __bf16 bf16;
typedef __attribute__((ext_vector_type(8))) __bf16 bf16x8;
typedef __attribute__((ext_vector_type(4))) float f32x4;

__device__ __forceinline__ void gload_lds16(const void* g, void* l) {
  __builtin_amdgcn_global_load_lds(
      (const __attribute__((address_space(1))) unsigned int*)g,
      (__attribute__((address_space(3))) unsigned int*)l, 16, 0, 0);
}

// ---------------- K1: setup = hist + x-cast + W1/W2 transpose-cast ----------------

#define CASTB (NT * 64 / 256)        // 5000 cast blocks (16 elems/thread)
#define TW1B (32 * 4 * NCLUS)        // 1280 W1-transpose blocks (32x128 tiles)
#define TW2B (16 * 4 * NCLUS)        // 640  W2-transpose blocks

// 32x128 tile transpose-cast: dst[b][j][i] = bf16(src[b][i][j])
__device__ __forceinline__ void tr_body(const float* __restrict__ s, bf16* __restrict__ d,
                                        int R, int Cc, int i0, int j0, float (*t)[128]) {
  int tid = threadIdx.x;
  int cr = tid >> 5;                 // 0..7
  int cc4 = (tid & 31) << 2;         // 0..124 step 4
#pragma unroll
  for (int yy = 0; yy < 32; yy += 8)
    *(f32x4*)&t[yy + cr][cc4] = *(const f32x4*)&s[(size_t)(i0 + yy + cr) * Cc + j0 + cc4];
  __syncthreads();
  int col = tid >> 1, h = (tid & 1) << 4;
  bf16 tmp[16];
#pragma unroll
  for (int k = 0; k < 16; ++k) tmp[k] = (bf16)t[h + k][col];
  *(bf16x8*)&d[(size_t)(j0 + col) * R + i0 + h] = *(bf16x8*)&tmp[0];
  *(bf16x8*)&d[(size_t)(j0 + col) * R + i0 + h + 8] = *(bf16x8*)&tmp[8];
}

__global__ __launch_bounds__(256) void setup_kernel(
    const int* __restrict__ cid, int* __restrict__ blkcnt,
    const float* __restrict__ x, bf16* __restrict__ xs,
    const float* __restrict__ W1, bf16* __restrict__ w1t,
    const float* __restrict__ W2, bf16* __restrict__ w2t) {
  __shared__ float t[32][128];
  __shared__ int wcnt[4][16];
  int b = blockIdx.x;
  int tid = threadIdx.x;
  if (b < NBS) {
    int lane = tid & 63, w = tid >> 6;
    int n = b * 256 + tid;
    int mycid = (n < NT) ? cid[n] : -1;
#pragma unroll
    for (int c = 0; c < NCLUS; ++c) {
      unsigned long long m = __ballot(mycid == c);
      if (lane == c) wcnt[w][c] = __popcll(m);
    }
    __syncthreads();
    if (tid < NCLUS)
      blkcnt[b * NCLUS + tid] =
          wcnt[0][tid] + wcnt[1][tid] + wcnt[2][tid] + wcnt[3][tid];
  } else if (b < NBS + CASTB) {
    int tt = (b - NBS) * 256 + tid;  // one thread per 16 elements
    size_t base = (size_t)tt << 4;
    if (base < (size_t)NT * DIM) {
      const f32x4* p = (const f32x4*)(x + base);
      f32x4 u0 = p[0], v0 = p[1], u1 = p[2], v1 = p[3];
      bf16x8 w0, w1;
      w0[0] = (bf16)u0[0]; w0[1] = (bf16)u0[1]; w0[2] = (bf16)u0[2]; w0[3] = (bf16)u0[3];
      w0[4] = (bf16)v0[0]; w0[5] = (bf16)v0[1]; w0[6] = (bf16)v0[2]; w0[7] = (bf16)v0[3];
      w1[0] = (bf16)u1[0]; w1[1] = (bf16)u1[1]; w1[2] = (bf16)u1[2]; w1[3] = (bf16)u1[3];
      w1[4] = (bf16)v1[0]; w1[5] = (bf16)v1[1]; w1[6] = (bf16)v1[2]; w1[7] = (bf16)v1[3];
      bf16* q = xs + base;
      *(bf16x8*)q = w0;
      *(bf16x8*)(q + 8) = w1;
    }
  } else if (b < NBS + CASTB + TW1B) {
    int bb = b - NBS - CASTB;        // z*128 + rt*4 + ct ; R=DIM rows, Cc=HID cols
    int z = bb >> 7, r = bb & 127, rt = r >> 2, ct = r & 3;
    tr_body(W1 + (size_t)z * DIM * HID, w1t + (size_t)z * DIM * HID,
            DIM, HID, rt * 32, ct * 128, t);
  } else {
    int bb = b - NBS - CASTB - TW1B; // z*64 + rt*4 + ct ; R=HID, Cc=HID
    int z = bb >> 6, r = bb & 63, rt = r >> 2, ct = r & 3;
    tr_body(W2 + (size_t)z * HID * HID, w2t + (size_t)z * HID * HID,
            HID, HID, rt * 32, ct * 128, t);
  }
}

// ---------------- K2: scatter (inlined prefix; extra blocks zero pool+score) ----------------

#define ZPB 20                       // zero blocks (NCLUS*HID/256)

__global__ __launch_bounds__(256) void scatter_kernel(
    const int* __restrict__ cid, const int* __restrict__ blkcnt,
    int* __restrict__ cnt, int* __restrict__ offs, int* __restrict__ order,
    float* __restrict__ pool, float* __restrict__ score) {
  int tid = threadIdx.x;
  int bx = blockIdx.x;
  if (bx >= NBS) {
    int i = (bx - NBS) * 256 + tid;
    if (i < NCLUS * HID) pool[i] = 0.f;
    if (bx == NBS && tid < 16) score[tid] = 0.f;
    return;
  }
  __shared__ int sbase[16];
  __shared__ int scnt[16];
  __shared__ int soffs[17];
  __shared__ int wcnt[4][16];
  __shared__ int wbase[4][16];
  int lane = tid & 63, w = tid >> 6;
  if (tid < NCLUS) {
    int base = 0, run = 0;
    for (int b = 0; b < NBS; ++b) {
      int v = blkcnt[b * NCLUS + tid];
      if (b < bx) base += v;
      run += v;
    }
    sbase[tid] = base;
    scnt[tid] = run;
  }
  __syncthreads();
  if (tid == 0) {
    int a = 0;
    for (int i = 0; i < NCLUS; ++i) { soffs[i] = a; a += scnt[i]; }
    soffs[NCLUS] = a;
  }
  __syncthreads();
  if (bx == 0 && tid <= NCLUS) {
    if (tid < NCLUS) cnt[tid] = scnt[tid];
    offs[tid] = soffs[tid];
  }
  int n = bx * 256 + tid;
  int mycid = (n < NT) ? cid[n] : -1;
  unsigned long long lmask = (lane == 63) ? ~0ull >> 1 : (1ull << lane) - 1;
  int myrank = 0;
#pragma unroll
  for (int c = 0; c < NCLUS; ++c) {
    unsigned long long m = __ballot(mycid == c);
    if (mycid == c) myrank = __popcll(m & lmask);
    if (lane == c) wcnt[w][c] = __popcll(m);
  }
  __syncthreads();
  if (tid < NCLUS) {
    int pre = sbase[tid];
#pragma unroll
    for (int ww = 0; ww < 4; ++ww) { wbase[ww][tid] = pre; pre += wcnt[ww][tid]; }
  }
  __syncthreads();
  if (n < NT) order[soffs[mycid] + wbase[w][mycid] + myrank] = n;
}

// XCD-grouping decode over NRTX tiles/cluster
__device__ __forceinline__ bool decode_grp(int d, int& c, int& rt, int& j) {
  int x8 = d & 7, s = d >> 3;
  int g = (s >> 2) * 8 + x8;
  if (g >= NRTX * NCLUS) return false;
  j = s & 3;
  c = g / NRTX;
  rt = g - c * NRTX;
  return true;
}

// ---------------- GEMM1: h1 = relu(x[order] @ W1[c]^T + b1[c]) ----------------
// 128x128 tile, BK=64, 4 waves, T2 both-sides XOR swizzle (rule 21).
// launch_bounds (256,2): VGPR 84, no spill (R15 lesson: min-waves 4 forced
// VGPR<=64 -> spills, +44 MB scratch writes).

__global__ __launch_bounds__(256, 2) void gemm1_kernel(
    const bf16* __restrict__ xs, const int* __restrict__ order,
    const bf16* __restrict__ w1t, const float* __restrict__ b1,
    const int* __restrict__ offs, const int* __restrict__ cnt, bf16* __restrict__ h1) {
  int c, rt, j;
  if (!decode_grp(blockIdx.x, c, rt, j)) return;
  int cntc = cnt[c];
  int row0 = rt * 128;
  if (row0 >= cntc) return;
  int seg = offs[c];
  int n0 = j * 128;

  __shared__ bf16 Als[128 * 64];  // [row][slot-swizzled k]
  __shared__ bf16 Bls[128 * 64];
  __shared__ int s_ord[128];

  int tid = threadIdx.x;
  int lane = tid & 63, wid = tid >> 6;
  if (tid < 128) {
    int ar = seg + row0 + tid; if (ar > NT - 1) ar = NT - 1;
    s_ord[tid] = order[ar];
  }
  __syncthreads();

  int wr = wid >> 1, wc = wid & 1;
  int rx = lane & 7, hi = lane >> 4;
  int kswz = ((lane & 7) ^ (lane >> 3)) << 3;   // source-swizzled 16B slot

  const bf16* aptr[4]; int aoff[4];
  const bf16* bptr[4]; int boff[4];
#pragma unroll
  for (int i = 0; i < 4; ++i) {
    int chunk = i * 4 + wid;              // 0..15, 8 rows x 64 k each
    int r = chunk * 8 + (lane >> 3);      // tile row 0..127
    aptr[i] = xs + (size_t)s_ord[r] * DIM + kswz;
    aoff[i] = chunk * 512;
    bptr[i] = w1t + (size_t)(c * HID + n0 + r) * DIM + kswz;
    boff[i] = chunk * 512;
  }

  f32x4 acc[4][4];
#pragma unroll
  for (int m = 0; m < 4; m++)
#pragma unroll
    for (int n = 0; n < 4; n++) acc[m][n] = {0.f, 0.f, 0.f, 0.f};

  for (int k0 = 0; k0 < DIM; k0 += 64) {
#pragma unroll
    for (int i = 0; i < 4; ++i) gload_lds16(aptr[i] + k0, &Als[aoff[i]]);
#pragma unroll
    for (int i = 0; i < 4; ++i) gload_lds16(bptr[i] + k0, &Bls[boff[i]]);
    __syncthreads();
#pragma unroll
    for (int ks = 0; ks < 2; ++ks) {
      int t16 = ks * 4 + hi;              // true 16B-slot index
      int ko = ((t16 ^ rx) << 3);         // swizzled read slot
      bf16x8 a[4], b[4];
#pragma unroll
      for (int m = 0; m < 4; m++)
        a[m] = *(const bf16x8*)(&Als[(wr * 64 + m * 16 + (lane & 15)) * 64 + ko]);
#pragma unroll
      for (int n = 0; n < 4; n++)
        b[n] = *(const bf16x8*)(&Bls[(wc * 64 + n * 16 + (lane & 15)) * 64 + ko]);
#pragma unroll
      for (int m = 0; m < 4; m++)
#pragma unroll
        for (int n = 0; n < 4; n++)
          acc[m][n] = __builtin_amdgcn_mfma_f32_16x16x32_bf16(a[m], b[n], acc[m][n], 0, 0, 0);
    }
    __syncthreads();
  }

  int valid = cntc - row0; if (valid > 128) valid = 128;
#pragma unroll
  for (int n = 0; n < 4; n++) {
    int col = n0 + wc * 64 + n * 16 + (lane & 15);
    float bias = b1[c * HID + col];
#pragma unroll
    for (int m = 0; m < 4; m++) {
      int rbase = wr * 64 + m * 16 + ((lane >> 4) << 2);
#pragma unroll
      for (int e = 0; e < 4; e++) {
        int r = rbase + e;
        if (r < valid) {
          float v = acc[m][n][e] + bias;
          h1[(size_t)(seg + row0 + r) * HID + col] = (bf16)(v > 0.f ? v : 0.f);
        }
      }
    }
  }
}

// ---------------- GEMM2: pool[c] += colsum(relu(h1 @ W2[c]^T + b2[c])) ----------------

__global__ __launch_bounds__(256, 2) void gemm2_kernel(
    const bf16* __restrict__ h1, const bf16* __restrict__ w2t, const float* __restrict__ b2,
    const int* __restrict__ offs, const int* __restrict__ cnt, float* __restrict__ pool) {
  int c, rt, j;
  if (!decode_grp(blockIdx.x, c, rt, j)) return;
  int cntc = cnt[c];
  int row0 = rt * 128;
  if (row0 >= cntc) return;
  int seg = offs[c];
  int n0 = j * 128;
  int valid = cntc - row0; if (valid > 128) valid = 128;

  __shared__ bf16 Als[128 * 64];
  __shared__ bf16 Bls[128 * 64];

  int tid = threadIdx.x;
  int lane = tid & 63, wid = tid >> 6;
  int wr = wid >> 1, wc = wid & 1;
  int rx = lane & 7, hi = lane >> 4;
  int kswz = ((lane & 7) ^ (lane >> 3)) << 3;

  const bf16* aptr[4]; int aoff[4];
  const bf16* bptr[4]; int boff[4];
#pragma unroll
  for (int i = 0; i < 4; ++i) {
    int chunk = i * 4 + wid;
    int r = chunk * 8 + (lane >> 3);
    int ar = seg + row0 + r; if (ar > NT - 1) ar = NT - 1;
    aptr[i] = h1 + (size_t)ar * HID + kswz;
    aoff[i] = chunk * 512;
    bptr[i] = w2t + (size_t)(c * HID + n0 + r) * HID + kswz;
    boff[i] = chunk * 512;
  }

  f32x4 acc[4][4];
#pragma unroll
  for (int m = 0; m < 4; m++)
#pragma unroll
    for (int n = 0; n < 4; n++) acc[m][n] = {0.f, 0.f, 0.f, 0.f};

  for (int k0 = 0; k0 < HID; k0 += 64) {
#pragma unroll
    for (int i = 0; i < 4; ++i) gload_lds16(aptr[i] + k0, &Als[aoff[i]]);
#pragma unroll
    for (int i = 0; i < 4; ++i) gload_lds16(bptr[i] + k0, &Bls[boff[i]]);
    __syncthreads();
#pragma unroll
    for (int ks = 0; ks < 2; ++ks) {
      int t16 = ks * 4 + hi;
      int ko = ((t16 ^ rx) << 3);
      bf16x8 a[4], b[4];
#pragma unroll
      for (int m = 0; m < 4; m++)
        a[m] = *(const bf16x8*)(&Als[(wr * 64 + m * 16 + (lane & 15)) * 64 + ko]);
#pragma unroll
      for (int n = 0; n < 4; n++)
        b[n] = *(const bf16x8*)(&Bls[(wc * 64 + n * 16 + (lane & 15)) * 64 + ko]);
#pragma unroll
      for (int m = 0; m < 4; m++)
#pragma unroll
        for (int n = 0; n < 4; n++)
          acc[m][n] = __builtin_amdgcn_mfma_f32_16x16x32_bf16(a[m], b[n], acc[m][n], 0, 0, 0);
    }
    __syncthreads();
  }

#pragma unroll
  for (int n = 0; n < 4; n++) {
    int col = n0 + wc * 64 + n * 16 + (lane & 15);
    float bias = b2[c * HID + col];
    float s = 0.f;
#pragma unroll
    for (int m = 0; m < 4; m++) {
      int rbase = wr * 64 + m * 16 + ((lane >> 4) << 2);
#pragma unroll
      for (int e = 0; e < 4; e++) {
        if (rbase + e < valid) {
          float v = acc[m][n][e] + bias;
          s += (v > 0.f ? v : 0.f);
        }
      }
    }
    s += __shfl_xor(s, 16);
    s += __shfl_xor(s, 32);
    if (lane < 16) atomicAdd(&pool[c * HID + n0 + wc * 64 + n * 16 + lane], s);
  }
}

// ---------------- tails (fp32, parallelized) ----------------

__global__ __launch_bounds__(256) void tail_fc(
    const float* __restrict__ pool, const int* __restrict__ cnt,
    const float* __restrict__ fcW, const float* __restrict__ fcb,
    float* __restrict__ hbuf) {
  int c = blockIdx.x >> 3;
  int jt = blockIdx.x & 7;
  __shared__ float hc[HID];
  __shared__ float red[4][64];
  int tid = threadIdx.x;
  float inv = 1.f / fmaxf((float)cnt[c], 1.f);
  for (int k = tid; k < HID; k += 256) hc[k] = pool[c * HID + k] * inv;
  __syncthreads();
  int jl = tid & 63, kg = tid >> 6;
  int j = jt * 64 + jl;
  float s = 0.f;
#pragma unroll 4
  for (int k = kg * 128; k < kg * 128 + 128; ++k) s += hc[k] * fcW[(size_t)k * HID + j];
  red[kg][jl] = s;
  __syncthreads();
  if (kg == 0) {
    float v = red[0][jl] + red[1][jl] + red[2][jl] + red[3][jl] + fcb[j];
    hbuf[c * HID + j] = fmaxf(v, 0.f);
  }
}

// 40 blocks: (cluster, 64-wide j slice); partial gated sums atomicAdd into score
__global__ __launch_bounds__(256) void tail_att(
    const float* __restrict__ hbuf,
    const float* __restrict__ Wa, const float* __restrict__ ba,
    const float* __restrict__ Wb, const float* __restrict__ bb,
    const float* __restrict__ Wc, const float* __restrict__ bc,
    float* __restrict__ score) {
  int c = blockIdx.x >> 2, js = blockIdx.x & 3;
  __shared__ float h[HID];
  __shared__ float ra[4][64];
  __shared__ float rb[4][64];
  __shared__ float sc[64];
  int tid = threadIdx.x;
  for (int k = tid; k < HID; k += 256) h[k] = hbuf[c * HID + k];
  __syncthreads();
  int jl = tid & 63, kg = tid >> 6;
  int j = js * 64 + jl;
  float sa = 0.f, sb = 0.f;
#pragma unroll 4
  for (int k = kg * 128; k < kg * 128 + 128; ++k) {
    float hv = h[k];
    sa += hv * Wa[(size_t)k * DATT_N + j];
    sb += hv * Wb[(size_t)k * DATT_N + j];
  }
  ra[kg][jl] = sa;
  rb[kg][jl] = sb;
  __syncthreads();
  if (kg == 0) {
    float va = ra[0][jl] + ra[1][jl] + ra[2][jl] + ra[3][jl] + ba[j];
    float vb = rb[0][jl] + rb[1][jl] + rb[2][jl] + rb[3][jl] + bb[j];
    float av = tanhf(va);
    float bv = 1.f / (1.f + expf(-vb));
    sc[jl] = av * bv * Wc[j];
  }
  __syncthreads();
  if (tid < 64) {
    float v = sc[tid];
#pragma unroll
    for (int w = 32; w > 0; w >>= 1) v += __shfl_xor(v, w);
    if (tid == 0) atomicAdd(&score[c], v + (js == 0 ? bc[0] : 0.f));
  }
}

// 8 blocks: softmax(score) -> hp -> 32-wide rho slice -> hr
__global__ __launch_bounds__(256) void tail_rho(
    const float* __restrict__ score, const float* __restrict__ hbuf,
    const float* __restrict__ rhoW, const float* __restrict__ rhob,
    float* __restrict__ hr) {
  int blk = blockIdx.x;  // 0..7
  __shared__ float Asm[NCLUS];
  __shared__ float hp[HID];
  __shared__ float rr[8][32];
  int tid = threadIdx.x;
  if (tid == 0) {
    float mx = -1e30f;
    for (int c = 0; c < NCLUS; c++) mx = fmaxf(mx, score[c]);
    float sum = 0.f, e[NCLUS];
    for (int c = 0; c < NCLUS; c++) { e[c] = expf(score[c] - mx); sum += e[c]; }
    for (int c = 0; c < NCLUS; c++) Asm[c] = e[c] / sum;
  }
  __syncthreads();
  for (int k = tid; k < HID; k += 256) {
    float s = 0.f;
#pragma unroll
    for (int c = 0; c < NCLUS; c++) s += Asm[c] * hbuf[c * HID + k];
    hp[k] = s;
  }
  __syncthreads();
  int jl = tid & 31, kg = tid >> 5;   // 8 k-groups of 64
  int j = blk * 32 + jl;
  float s = 0.f;
#pragma unroll 4
  for (int k = kg * 64; k < kg * 64 + 64; ++k) s += hp[k] * rhoW[(size_t)k * DATT_N + j];
  rr[kg][jl] = s;
  __syncthreads();
  if (kg == 0) {
    float v = rr[0][jl] + rr[1][jl] + rr[2][jl] + rr[3][jl] +
              rr[4][jl] + rr[5][jl] + rr[6][jl] + rr[7][jl] + rhob[j];
    hr[j] = fmaxf(v, 0.f);
  }
}

// 1 block: classifier -> softmax -> argmax -> out
__global__ __launch_bounds__(256) void tail_cls(
    const float* __restrict__ hr, const float* __restrict__ clsW,
    const float* __restrict__ clsb, float* __restrict__ out) {
  __shared__ float lg[NCLS_N];
  int tid = threadIdx.x;
  if (tid < NCLS_N * 64) {
    int t = tid >> 6, l = tid & 63;
    float cs = 0.f;
    for (int j = l; j < DATT_N; j += 64) cs += hr[j] * clsW[j * NCLS_N + t];
#pragma unroll
    for (int w = 32; w > 0; w >>= 1) cs += __shfl_xor(cs, w);
    if (l == 0) lg[t] = cs + clsb[t];
  }
  __syncthreads();
  if (tid == 0) {
    float mx = lg[0];
    int am = 0;
    for (int t = 1; t < NCLS_N; t++) if (lg[t] > mx) { mx = lg[t]; am = t; }
    float sum = 0.f, e[NCLS_N];
    for (int t = 0; t < NCLS_N; t++) { e[t] = expf(lg[t] - mx); sum += e[t]; }
    for (int t = 0; t < NCLS_N; t++) {
      out[t] = lg[t];
      out[NCLS_N + t] = e[t] / sum;
    }
    out[2 * NCLS_N] = (float)am;
  }
}

// ---------------- launch ----------------

extern "C" void kernel_launch(void* const* d_in, const int* in_sizes, int n_in,
                              void* d_out, int out_size, void* d_ws, size_t ws_size,
                              hipStream_t stream) {
  const float* x    = (const float*)d_in[0];
  const int*   cid  = (const int*)d_in[1];
  const float* W1   = (const float*)d_in[2];
  const float* b1   = (const float*)d_in[3];
  const float* W2   = (const float*)d_in[4];
  const float* b2   = (const float*)d_in[5];
  const float* fcW  = (const float*)d_in[6];
  const float* fcb  = (const float*)d_in[7];
  const float* Wa   = (const float*)d_in[8];
  const float* ba   = (const float*)d_in[9];
  const float* Wb   = (const float*)d_in[10];
  const float* bb   = (const float*)d_in[11];
  const float* Wc   = (const float*)d_in[12];
  const float* bc   = (const float*)d_in[13];
  const float* rhoW = (const float*)d_in[14];
  const float* rhob = (const float*)d_in[15];
  const float* clsW = (const float*)d_in[16];
  const float* clsb = (const float*)d_in[17];
  float* out = (float*)d_out;

  char* ws = (char*)d_ws;
  int*   cnt     = (int*)(ws + 0);
  int*   offs    = (int*)(ws + 64);
  float* score   = (float*)(ws + 128);                  // 16 floats
  float* hr      = (float*)(ws + 1024);                 // DATT_N floats
  int*   blkcnt  = (int*)(ws + 4096);                   // NBS*NCLUS = 790 ints
  int*   order   = (int*)(ws + 8192);                   // NT ints
  float* pool    = (float*)(ws + 8192 + 80000);
  float* hbuf    = (float*)(ws + 8192 + 80000 + NCLUS * HID * 4);
  size_t o = 8192 + 80000 + 2ull * NCLUS * HID * 4;
  o = (o + 255) & ~(size_t)255;
  bf16* w1t = (bf16*)(ws + o); o += (size_t)NCLUS * HID * DIM * 2;
  bf16* w2t = (bf16*)(ws + o); o += (size_t)NCLUS * HID * HID * 2;
  bf16* h1  = (bf16*)(ws + o); o += (size_t)NT * HID * 2;
  bf16* xs  = (bf16*)(ws + o); o += (size_t)NT * DIM * 2;

  setup_kernel<<<dim3(NBS + CASTB + TW1B + TW2B), dim3(256), 0, stream>>>(
      cid, blkcnt, x, xs, W1, w1t, W2, w2t);
  scatter_kernel<<<dim3(NBS + ZPB), dim3(256), 0, stream>>>(
      cid, blkcnt, cnt, offs, order, pool, score);

  int nblk = 8 * ((NRTX * NCLUS + 7) / 8) * 4;   // 1600
  gemm1_kernel<<<dim3(nblk), dim3(256), 0, stream>>>(xs, order, w1t, b1, offs, cnt, h1);
  gemm2_kernel<<<dim3(nblk), dim3(256), 0, stream>>>(h1, w2t, b2, offs, cnt, pool);

  tail_fc<<<dim3(NCLUS * 8), dim3(256), 0, stream>>>(pool, cnt, fcW, fcb, hbuf);
  tail_att<<<dim3(NCLUS * 4), dim3(256), 0, stream>>>(hbuf, Wa, ba, Wb, bb, Wc, bc, score);
  tail_rho<<<dim3(8), dim3(256), 0, stream>>>(score, hbuf, rhoW, rhob, hr);
  tail_cls<<<dim3(1), dim3(256), 0, stream>>>(hr, clsW, clsb, out);
}